// Round 1
// baseline (646.027 us; speedup 1.0000x reference)
//
#include <hip/hip_runtime.h>
#include <stdint.h>

// Problem constants
#define LQ   2048
#define LKK  2048
#define DD   512
#define NB   16
static constexpr float TEMP_INV = 1.0f / 22.627416997969522f;

typedef __bf16  bf16x8 __attribute__((ext_vector_type(8)));
typedef float   f32x4  __attribute__((ext_vector_type(4)));
typedef unsigned short u16x4 __attribute__((ext_vector_type(4)));

__device__ __forceinline__ unsigned short f2bf(float f) {
  unsigned u = __builtin_bit_cast(unsigned, f);
  u += 0x7fffu + ((u >> 16) & 1u);      // round-to-nearest-even
  return (unsigned short)(u >> 16);
}

__device__ __forceinline__ void gload16(const void* g, void* l) {
  __builtin_amdgcn_global_load_lds(
      (const __attribute__((address_space(1))) void*)g,
      (__attribute__((address_space(3))) void*)l, 16, 0, 0);
}

// ---------------------------------------------------------------------------
// Projection GEMM: C[m][n] = sum_k X[m][k] * W[n][k] + bias[n]   (bf16 out)
// X: f32 [M][512], W: f32 [512][512], out: bf16 [M][512]
// ---------------------------------------------------------------------------
__global__ __launch_bounds__(256) void proj_kernel(
    const float* __restrict__ X, const float* __restrict__ W,
    const float* __restrict__ bias, unsigned short* __restrict__ out)
{
  __shared__ unsigned short As[128 * 32];
  __shared__ unsigned short Bs[128 * 32];
  const int t = threadIdx.x;
  const int lane = t & 63;
  const int w = t >> 6;
  const int wm = w >> 1, wn = w & 1;
  const int m0 = blockIdx.x * 128;
  const int n0 = blockIdx.y * 128;
  const int sr = t >> 1;
  const int sc = (t & 1) * 16;

  f32x4 acc[4][4] = {};

  for (int k0 = 0; k0 < 512; k0 += 32) {
    const float* ga = X + (size_t)(m0 + sr) * 512 + k0 + sc;
    const float* gb = W + (size_t)(n0 + sr) * 512 + k0 + sc;
#pragma unroll
    for (int i = 0; i < 4; ++i) {
      f32x4 av = *(const f32x4*)(ga + 4 * i);
      f32x4 bv = *(const f32x4*)(gb + 4 * i);
      u16x4 ap = { f2bf(av[0]), f2bf(av[1]), f2bf(av[2]), f2bf(av[3]) };
      u16x4 bp = { f2bf(bv[0]), f2bf(bv[1]), f2bf(bv[2]), f2bf(bv[3]) };
      *(u16x4*)&As[sr * 32 + sc + 4 * i] = ap;
      *(u16x4*)&Bs[sr * 32 + sc + 4 * i] = bp;
    }
    __syncthreads();
    bf16x8 af[4], bfr[4];
#pragma unroll
    for (int i = 0; i < 4; ++i)
      af[i] = *(const bf16x8*)&As[(wm * 64 + i * 16 + (lane & 15)) * 32 + (lane >> 4) * 8];
#pragma unroll
    for (int j = 0; j < 4; ++j)
      bfr[j] = *(const bf16x8*)&Bs[(wn * 64 + j * 16 + (lane & 15)) * 32 + (lane >> 4) * 8];
#pragma unroll
    for (int i = 0; i < 4; ++i)
#pragma unroll
      for (int j = 0; j < 4; ++j)
        acc[i][j] = __builtin_amdgcn_mfma_f32_16x16x32_bf16(af[i], bfr[j], acc[i][j], 0, 0, 0);
    __syncthreads();
  }

#pragma unroll
  for (int j = 0; j < 4; ++j) {
    const int col = n0 + wn * 64 + j * 16 + (lane & 15);
    const float bv = bias[col];
#pragma unroll
    for (int i = 0; i < 4; ++i) {
      const int row = m0 + wm * 64 + i * 16 + (lane >> 4) * 4;
#pragma unroll
      for (int r = 0; r < 4; ++r)
        out[(size_t)(row + r) * 512 + col] = f2bf(acc[i][j][r] + bv);
    }
  }
}

// ---------------------------------------------------------------------------
// QK^T GEMM: S[b][m][n] = (sum_a qp[b][m][a]*kp[b][n][a]) / TEMP  (f32 out)
// ---------------------------------------------------------------------------
__global__ __launch_bounds__(256) void qk_kernel(
    const unsigned short* __restrict__ QP, const unsigned short* __restrict__ KP,
    float* __restrict__ S)
{
  __shared__ unsigned short As[128 * 32];
  __shared__ unsigned short Bs[128 * 32];
  const int t = threadIdx.x;
  const int lane = t & 63;
  const int w = t >> 6;
  const int wm = w >> 1, wn = w & 1;
  const int b = blockIdx.z;
  const int m0 = blockIdx.x * 128;
  const int n0 = blockIdx.y * 128;
  const unsigned short* A  = QP + (size_t)b * LQ * DD;
  const unsigned short* Bm = KP + (size_t)b * LKK * DD;

  f32x4 acc[4][4] = {};

  for (int k0 = 0; k0 < 512; k0 += 32) {
#pragma unroll
    for (int it = 0; it < 2; ++it) {
      const int ci = w * 64 + lane + it * 256;   // chunk 0..511
      const int row = ci >> 2, c8 = (ci & 3) * 8;
      gload16(A  + (size_t)(m0 + row) * 512 + k0 + c8, &As[(w * 64 + it * 256) * 8]);
      gload16(Bm + (size_t)(n0 + row) * 512 + k0 + c8, &Bs[(w * 64 + it * 256) * 8]);
    }
    __syncthreads();
    bf16x8 af[4], bfr[4];
#pragma unroll
    for (int i = 0; i < 4; ++i)
      af[i] = *(const bf16x8*)&As[(wm * 64 + i * 16 + (lane & 15)) * 32 + (lane >> 4) * 8];
#pragma unroll
    for (int j = 0; j < 4; ++j)
      bfr[j] = *(const bf16x8*)&Bs[(wn * 64 + j * 16 + (lane & 15)) * 32 + (lane >> 4) * 8];
#pragma unroll
    for (int i = 0; i < 4; ++i)
#pragma unroll
      for (int j = 0; j < 4; ++j)
        acc[i][j] = __builtin_amdgcn_mfma_f32_16x16x32_bf16(af[i], bfr[j], acc[i][j], 0, 0, 0);
    __syncthreads();
  }

  float* Sb = S + (size_t)b * LQ * LKK;
#pragma unroll
  for (int j = 0; j < 4; ++j) {
    const int col = n0 + wn * 64 + j * 16 + (lane & 15);
#pragma unroll
    for (int i = 0; i < 4; ++i) {
      const int row = m0 + wm * 64 + i * 16 + (lane >> 4) * 4;
#pragma unroll
      for (int r = 0; r < 4; ++r)
        Sb[(size_t)(row + r) * LKK + col] = acc[i][j][r] * TEMP_INV;
    }
  }
}

// ---------------------------------------------------------------------------
// V transpose: V f32 [b][2048][512] -> VT bf16 [b][512][2048]
// ---------------------------------------------------------------------------
__global__ __launch_bounds__(256) void vtrans_kernel(
    const float* __restrict__ V, unsigned short* __restrict__ VT)
{
  __shared__ unsigned short tile[32][33];
  const int b = blockIdx.z;
  const int j0 = blockIdx.x * 32;   // LK
  const int d0 = blockIdx.y * 32;   // D
  const int tx = threadIdx.x & 31, ty = threadIdx.x >> 5;
  const float* Vb = V + (size_t)b * LKK * DD;
  unsigned short* VTb = VT + (size_t)b * DD * LKK;
#pragma unroll
  for (int r = 0; r < 4; ++r)
    tile[ty + 8 * r][tx] = f2bf(Vb[(size_t)(j0 + ty + 8 * r) * DD + d0 + tx]);
  __syncthreads();
#pragma unroll
  for (int r = 0; r < 4; ++r)
    VTb[(size_t)(d0 + ty + 8 * r) * LKK + j0 + tx] = tile[tx][ty + 8 * r];
}

// ---------------------------------------------------------------------------
// Mask dtype detection: flag = bit0 (nonzero byte at pos%4!=0) | bit1<<1
// (nonzero byte at pos%4==0).  bool=>3, int32=>2, f32=>1
// ---------------------------------------------------------------------------
__global__ void detect_mask_kernel(const unsigned char* __restrict__ m, int* flag)
{
  __shared__ int c0, c1;
  if (threadIdx.x == 0) { c0 = 0; c1 = 0; }
  __syncthreads();
  int l0 = 0, l1 = 0;
  for (int i = threadIdx.x; i < 16384; i += 256) {
    if (m[i] != 0) { if (i & 3) l0 = 1; else l1 = 1; }
  }
  if (l0) atomicOr(&c0, 1);
  if (l1) atomicOr(&c1, 1);
  __syncthreads();
  if (threadIdx.x == 0) *flag = c0 | (c1 << 1);
}

// ---------------------------------------------------------------------------
// Row softmax with mask (in-place on S), NaN-row -> zeros
// ---------------------------------------------------------------------------
__global__ __launch_bounds__(256) void softmax_kernel(
    float* __restrict__ S, const void* __restrict__ maskp,
    const int* __restrict__ flagp)
{
  const size_t row = blockIdx.x;
  const int t = threadIdx.x;
  float* Sr = S + row * (size_t)LKK;
  const int flag = *flagp;

  bool ok[8];
  float x[8];
  if (flag == 3) {            // 1-byte bool
    const unsigned char* mb = (const unsigned char*)maskp + row * (size_t)LKK;
#pragma unroll
    for (int s = 0; s < 8; ++s) ok[s] = (mb[t + 256 * s] == 0);
  } else if (flag == 2) {     // int32
    const int* mi = (const int*)maskp + row * (size_t)LKK;
#pragma unroll
    for (int s = 0; s < 8; ++s) ok[s] = (mi[t + 256 * s] == 0);
  } else {                    // f32 0/1
    const float* mf = (const float*)maskp + row * (size_t)LKK;
#pragma unroll
    for (int s = 0; s < 8; ++s) ok[s] = (mf[t + 256 * s] == 0.0f);
  }

  float mx = -INFINITY;
#pragma unroll
  for (int s = 0; s < 8; ++s) {
    x[s] = Sr[t + 256 * s];
    if (ok[s]) mx = fmaxf(mx, x[s]);
  }
#pragma unroll
  for (int off = 32; off > 0; off >>= 1) mx = fmaxf(mx, __shfl_xor(mx, off));
  __shared__ float redm[4], reds[4];
  if ((t & 63) == 0) redm[t >> 6] = mx;
  __syncthreads();
  mx = fmaxf(fmaxf(redm[0], redm[1]), fmaxf(redm[2], redm[3]));

  float e[8], sum = 0.f;
#pragma unroll
  for (int s = 0; s < 8; ++s) {
    e[s] = ok[s] ? __expf(x[s] - mx) : 0.0f;
    sum += e[s];
  }
#pragma unroll
  for (int off = 32; off > 0; off >>= 1) sum += __shfl_xor(sum, off);
  if ((t & 63) == 0) reds[t >> 6] = sum;
  __syncthreads();
  sum = reds[0] + reds[1] + reds[2] + reds[3];
  const float inv = (sum > 0.0f) ? 1.0f / sum : 0.0f;
#pragma unroll
  for (int s = 0; s < 8; ++s) Sr[t + 256 * s] = e[s] * inv;
}

// ---------------------------------------------------------------------------
// PV GEMM: O[b][m][d] = sum_j attn[b][m][j] * V[b][j][d]
// attn f32 (reg-staged -> bf16), VT bf16 [b][512][2048] via global_load_lds
// ---------------------------------------------------------------------------
__global__ __launch_bounds__(256) void pv_kernel(
    const float* __restrict__ S, const unsigned short* __restrict__ VT,
    float* __restrict__ O)
{
  __shared__ unsigned short As[128 * 32];
  __shared__ unsigned short Bs[128 * 32];
  const int t = threadIdx.x;
  const int lane = t & 63;
  const int w = t >> 6;
  const int wm = w >> 1, wn = w & 1;
  const int b = blockIdx.z;
  const int m0 = blockIdx.x * 128;
  const int n0 = blockIdx.y * 128;
  const float* A = S + (size_t)b * LQ * LKK;
  const unsigned short* Bm = VT + (size_t)b * DD * LKK;
  const int sr = t >> 1;
  const int sc = (t & 1) * 16;

  f32x4 acc[4][4] = {};

  for (int k0 = 0; k0 < LKK; k0 += 32) {
    const float* ga = A + (size_t)(m0 + sr) * LKK + k0 + sc;
#pragma unroll
    for (int i = 0; i < 4; ++i) {
      f32x4 av = *(const f32x4*)(ga + 4 * i);
      u16x4 ap = { f2bf(av[0]), f2bf(av[1]), f2bf(av[2]), f2bf(av[3]) };
      *(u16x4*)&As[sr * 32 + sc + 4 * i] = ap;
    }
#pragma unroll
    for (int it = 0; it < 2; ++it) {
      const int ci = w * 64 + lane + it * 256;
      const int row = ci >> 2, c8 = (ci & 3) * 8;
      gload16(Bm + (size_t)(n0 + row) * LKK + k0 + c8, &Bs[(w * 64 + it * 256) * 8]);
    }
    __syncthreads();
    bf16x8 af[4], bfr[4];
#pragma unroll
    for (int i = 0; i < 4; ++i)
      af[i] = *(const bf16x8*)&As[(wm * 64 + i * 16 + (lane & 15)) * 32 + (lane >> 4) * 8];
#pragma unroll
    for (int j = 0; j < 4; ++j)
      bfr[j] = *(const bf16x8*)&Bs[(wn * 64 + j * 16 + (lane & 15)) * 32 + (lane >> 4) * 8];
#pragma unroll
    for (int i = 0; i < 4; ++i)
#pragma unroll
      for (int j = 0; j < 4; ++j)
        acc[i][j] = __builtin_amdgcn_mfma_f32_16x16x32_bf16(af[i], bfr[j], acc[i][j], 0, 0, 0);
    __syncthreads();
  }

  float* Ob = O + (size_t)b * LQ * DD;
#pragma unroll
  for (int j = 0; j < 4; ++j) {
    const int col = n0 + wn * 64 + j * 16 + (lane & 15);
#pragma unroll
    for (int i = 0; i < 4; ++i) {
      const int row = m0 + wm * 64 + i * 16 + (lane >> 4) * 4;
#pragma unroll
      for (int r = 0; r < 4; ++r)
        Ob[(size_t)(row + r) * DD + col] = acc[i][j][r];
    }
  }
}

// ---------------------------------------------------------------------------
extern "C" void kernel_launch(void* const* d_in, const int* in_sizes, int n_in,
                              void* d_out, int out_size, void* d_ws, size_t ws_size,
                              hipStream_t stream)
{
  const float* q  = (const float*)d_in[0];
  const float* k  = (const float*)d_in[1];
  const float* v  = (const float*)d_in[2];
  const void*  mask = d_in[3];
  const float* Wq = (const float*)d_in[4];
  const float* bq = (const float*)d_in[5];
  const float* Wk = (const float*)d_in[6];
  const float* bk = (const float*)d_in[7];

  float* out0 = (float*)d_out;                       // [16,2048,512]
  float* attn = out0 + (size_t)NB * LQ * DD;         // [16,2048,2048]

  unsigned short* qp = (unsigned short*)d_ws;        // bf16 [16,2048,512]
  unsigned short* kp = qp + (size_t)NB * LQ * DD;
  unsigned short* vt = kp + (size_t)NB * LKK * DD;   // bf16 [16,512,2048]
  int* flag = (int*)(vt + (size_t)NB * DD * LKK);

  detect_mask_kernel<<<1, 256, 0, stream>>>((const unsigned char*)mask, flag);
  proj_kernel<<<dim3(256, 4), 256, 0, stream>>>(q, Wq, bq, qp);
  proj_kernel<<<dim3(256, 4), 256, 0, stream>>>(k, Wk, bk, kp);
  vtrans_kernel<<<dim3(64, 16, NB), 256, 0, stream>>>(v, vt);
  qk_kernel<<<dim3(16, 16, NB), 256, 0, stream>>>(qp, kp, attn);
  softmax_kernel<<<NB * LQ, 256, 0, stream>>>(attn, mask, flag);
  pv_kernel<<<dim3(16, 4, NB), 256, 0, stream>>>(attn, vt, out0);
}